// Round 6
// baseline (564.445 us; speedup 1.0000x reference)
//
#include <hip/hip_runtime.h>
#include <hip/hip_bf16.h>

// GCN forward: StandardScaler -> GCNConv(relu) -> GCNConv -> mean-pool -> Linear
// N=20000 nodes, E=160000 edges, D=512 all layers, G=128 graphs.
//
// Algebraic restructure: everything after conv1's ReLU is linear, and row-ops
// (Agg, pool) commute with col-ops (@W2, @Wlin):
//   out = pool(Agg(g@W2)+b2) @ Wlin + blin
//       = pool(Agg(g)) @ (W2@Wlin) + (b2@Wlin + blin)
// so the 20000x512x512 GEMM2 collapses to a small post-pool GEMM, plus one
// precomputed 512^3 GEMM (Wc = W2@Wlin) overlapping the stats kernels.
// pool(Agg(g)) is ONE fused kernel (batch sorted -> contiguous graph ranges),
// sliced 16x per graph for occupancy (latency-hiding TLP), partials summed
// deterministically in final_kernel. Partial buffer aliases dead h buffer.
//
// Index dtype robustness: if the harness hands raw int64 buffers, in_sizes
// doubles; we then read stride-2 (little-endian low word).

#define NN 20000
#define NE 160000
#define DD 512
#define NG 128
#define PSLICE 16

// ---------------- column stats (mean / rstd) ----------------
__global__ __launch_bounds__(256) void colstats_kernel(const float* __restrict__ x,
                                                       float* __restrict__ colsum,
                                                       float* __restrict__ colsq) {
    int c = blockIdx.x * 256 + threadIdx.x;          // 2 blocks in x cover 512 cols
    int r0 = blockIdx.y * 500;                       // 40 blocks in y cover 20000 rows
    float s = 0.f, sq = 0.f;
    for (int r = r0; r < r0 + 500; ++r) {
        float v = x[(size_t)r * DD + c];
        s += v;
        sq = fmaf(v, v, sq);
    }
    atomicAdd(&colsum[c], s);
    atomicAdd(&colsq[c], sq);
}

__global__ void finalize_kernel(const float* __restrict__ colsum, const float* __restrict__ colsq,
                                float* __restrict__ mu, float* __restrict__ rstd) {
    int c = threadIdx.x;                              // 512 threads
    float m = colsum[c] * (1.0f / NN);
    float var = colsq[c] * (1.0f / NN) - m * m;
    float sd = sqrtf(fmaxf(var, 0.0f));
    mu[c] = m;
    rstd[c] = (sd > 0.0f) ? (1.0f / sd) : 1.0f;       // ref: divide by where(sd>0, sd, 1)
}

// W1s[k][n] = rstd[k] * W1[k][n]
__global__ void scalew_kernel(const float* __restrict__ W1, const float* __restrict__ rstd,
                              float* __restrict__ W1s) {
    int idx = blockIdx.x * 256 + threadIdx.x;         // 1024 blocks
    int k = idx >> 9;
    W1s[idx] = W1[idx] * rstd[k];
}

// c1[n] = -sum_k mu[k] * W1s[k][n]
__global__ __launch_bounds__(256) void c1_kernel(const float* __restrict__ W1s,
                                                 const float* __restrict__ mu,
                                                 float* __restrict__ c1v) {
    int n = blockIdx.x;
    float s = 0.f;
    for (int k = threadIdx.x; k < DD; k += 256)
        s = fmaf(mu[k], W1s[(size_t)k * DD + n], s);
    __shared__ float red[256];
    red[threadIdx.x] = s;
    __syncthreads();
    for (int off = 128; off > 0; off >>= 1) {
        if (threadIdx.x < off) red[threadIdx.x] += red[threadIdx.x + off];
        __syncthreads();
    }
    if (threadIdx.x == 0) c1v[n] = -red[0];
}

// bc[n] = blin[n] + sum_k b2[k] * Wlin[k][n]
__global__ __launch_bounds__(256) void bc_kernel(const float* __restrict__ Wlin,
                                                 const float* __restrict__ b2,
                                                 const float* __restrict__ blin,
                                                 float* __restrict__ bc) {
    int n = blockIdx.x;
    float s = 0.f;
    for (int k = threadIdx.x; k < DD; k += 256)
        s = fmaf(b2[k], Wlin[(size_t)k * DD + n], s);
    __shared__ float red[256];
    red[threadIdx.x] = s;
    __syncthreads();
    for (int off = 128; off > 0; off >>= 1) {
        if (threadIdx.x < off) red[threadIdx.x] += red[threadIdx.x + off];
        __syncthreads();
    }
    if (threadIdx.x == 0) bc[n] = blin[n] + red[0];
}

// ---------------- graph structure (CSR by destination) ----------------
__global__ void deginit_kernel(int* __restrict__ deg) {
    int i = blockIdx.x * 256 + threadIdx.x;
    if (i < NN) deg[i] = 1;                           // self-loop contributes 1
}

__global__ void degcount_kernel(const int* __restrict__ dst, int* __restrict__ deg, int es) {
    int e = blockIdx.x * 256 + threadIdx.x;
    if (e < NE) {
        int d = dst[(size_t)e * es];
        if ((unsigned)d < (unsigned)NN) atomicAdd(&deg[d], 1);
    }
}

__global__ void dis_kernel(const int* __restrict__ deg, float* __restrict__ dis) {
    int i = blockIdx.x * 256 + threadIdx.x;
    if (i < NN) dis[i] = rsqrtf((float)deg[i]);       // deg >= 1 always
}

// exclusive scan of indeg (deg-1) over 20000 entries; writes rowptr[0..20000] and cursor copy
__global__ __launch_bounds__(1024) void scan_kernel(const int* __restrict__ deg,
                                                    int* __restrict__ rowptr,
                                                    int* __restrict__ cursor) {
    const int PER = 20;                               // 1024*20 = 20480 >= 20001
    __shared__ int sums[1024];
    int t = threadIdx.x;
    int base = t * PER;
    int local[PER];
    int s = 0;
#pragma unroll
    for (int j = 0; j < PER; ++j) {
        int idx = base + j;
        int v = (idx < NN) ? (deg[idx] - 1) : 0;
        local[j] = s;
        s += v;
    }
    sums[t] = s;
    __syncthreads();
    for (int off = 1; off < 1024; off <<= 1) {
        int v = (t >= off) ? sums[t - off] : 0;
        __syncthreads();
        sums[t] += v;
        __syncthreads();
    }
    int prefix = (t == 0) ? 0 : sums[t - 1];
#pragma unroll
    for (int j = 0; j < PER; ++j) {
        int idx = base + j;
        if (idx <= NN) {
            int val = prefix + local[j];
            rowptr[idx] = val;
            if (idx < NN) cursor[idx] = val;
        }
    }
}

__global__ void scatter_kernel(const int* __restrict__ src, const int* __restrict__ dst,
                               int* __restrict__ cursor, int* __restrict__ csrsrc, int es) {
    int e = blockIdx.x * 256 + threadIdx.x;
    if (e < NE) {
        int d = dst[(size_t)e * es];
        int sN = src[(size_t)e * es];
        if ((unsigned)d < (unsigned)NN && (unsigned)sN < (unsigned)NN) {
            int slot = atomicAdd(&cursor[d], 1);
            csrsrc[slot] = sN;
        }
    }
}

// ---------------- fp32 GEMM: C[M x 512] = A[M x 512] @ B[512 x 512] (+ bias row) ----------------
// BM=128, BN=128, BK=16; 256 threads, 8x8 micro-tile split 4+4 rows/cols for bank-friendly b128.
#define BM 128
#define BN 128
#define BK 16

__global__ __launch_bounds__(256) void gemm_f32_kernel(const float* __restrict__ A,
                                                       const float* __restrict__ B,
                                                       float* __restrict__ C,
                                                       const float* __restrict__ bias,
                                                       int M) {
    __shared__ float As[BK][BM + 4];                  // transposed A tile, padded
    __shared__ float Bs[BK][BN];
    int tid = threadIdx.x;
    int tx = tid & 15, ty = tid >> 4;
    int rowBase = blockIdx.x * BM;
    int colBase = blockIdx.y * BN;

    float acc[8][8];
#pragma unroll
    for (int i = 0; i < 8; ++i)
#pragma unroll
        for (int j = 0; j < 8; ++j) acc[i][j] = 0.f;

    for (int k0 = 0; k0 < DD; k0 += BK) {
#pragma unroll
        for (int i = 0; i < 2; ++i) {                 // A tile: 512 float4 loads
            int lin = tid + i * 256;
            int r = lin >> 2, c4 = (lin & 3) * 4;
            float4 v = make_float4(0.f, 0.f, 0.f, 0.f);
            int gr = rowBase + r;
            if (gr < M) v = *(const float4*)(A + (size_t)gr * DD + k0 + c4);
            As[c4 + 0][r] = v.x;
            As[c4 + 1][r] = v.y;
            As[c4 + 2][r] = v.z;
            As[c4 + 3][r] = v.w;
        }
#pragma unroll
        for (int i = 0; i < 2; ++i) {                 // B tile: 512 float4 loads
            int lin = tid + i * 256;
            int kc = lin >> 5, c4 = (lin & 31) * 4;
            float4 v = *(const float4*)(B + (size_t)(k0 + kc) * DD + colBase + c4);
            *(float4*)&Bs[kc][c4] = v;
        }
        __syncthreads();
#pragma unroll
        for (int kk = 0; kk < BK; ++kk) {
            float a[8], b[8];
            *(float4*)&a[0] = *(const float4*)&As[kk][ty * 4];
            *(float4*)&a[4] = *(const float4*)&As[kk][64 + ty * 4];
            *(float4*)&b[0] = *(const float4*)&Bs[kk][tx * 4];
            *(float4*)&b[4] = *(const float4*)&Bs[kk][64 + tx * 4];
#pragma unroll
            for (int i = 0; i < 8; ++i)
#pragma unroll
                for (int j = 0; j < 8; ++j) acc[i][j] = fmaf(a[i], b[j], acc[i][j]);
        }
        __syncthreads();
    }

#pragma unroll
    for (int i = 0; i < 8; ++i) {
        int r = (i < 4) ? (ty * 4 + i) : (64 + ty * 4 + (i - 4));
        int gr = rowBase + r;
        if (gr >= M) continue;
        int c0 = colBase + tx * 4;
        int c1c = colBase + 64 + tx * 4;
        float4 o0, o1;
        if (bias) {
            o0 = make_float4(acc[i][0] + bias[c0 + 0], acc[i][1] + bias[c0 + 1],
                             acc[i][2] + bias[c0 + 2], acc[i][3] + bias[c0 + 3]);
            o1 = make_float4(acc[i][4] + bias[c1c + 0], acc[i][5] + bias[c1c + 1],
                             acc[i][6] + bias[c1c + 2], acc[i][7] + bias[c1c + 3]);
        } else {
            o0 = make_float4(acc[i][0], acc[i][1], acc[i][2], acc[i][3]);
            o1 = make_float4(acc[i][4], acc[i][5], acc[i][6], acc[i][7]);
        }
        *(float4*)(C + (size_t)gr * DD + c0) = o0;
        *(float4*)(C + (size_t)gr * DD + c1c) = o1;
    }
}

// ---------------- edge aggregation: out[i] = di*(di*h[i] + sum_e dis[s]*h[s]) + b [relu] ----
// Gather chain (csrsrc[e] -> dis[s] -> h[s][f]) is 3-deep; software-pipeline the
// index+scale fetch one iteration ahead so it issues under the h-row loads.
__global__ __launch_bounds__(256) void agg_kernel(const float* __restrict__ h,
                                                  float* __restrict__ out,
                                                  const float* __restrict__ dis,
                                                  const int* __restrict__ rowptr,
                                                  const int* __restrict__ csrsrc,
                                                  const float* __restrict__ bias,
                                                  int relu) {
    int i = blockIdx.x;
    int f = threadIdx.x * 2;
    float di = dis[i];
    float2 v = *(const float2*)(h + (size_t)i * DD + f);
    float accx = di * v.x, accy = di * v.y;
    int e0 = rowptr[i], e1 = rowptr[i + 1];
    if (e0 < e1) {
        int s = csrsrc[e0];
        float ds = dis[s];
        for (int e = e0; e < e1; ++e) {
            int   sn = 0;
            float dn = 0.f;
            if (e + 1 < e1) { sn = csrsrc[e + 1]; dn = dis[sn]; }   // prefetch next
            float2 hv = *(const float2*)(h + (size_t)s * DD + f);
            accx = fmaf(ds, hv.x, accx);
            accy = fmaf(ds, hv.y, accy);
            s = sn; ds = dn;
        }
    }
    accx = fmaf(di, accx, bias[f]);
    accy = fmaf(di, accy, bias[f + 1]);
    if (relu) { accx = fmaxf(accx, 0.f); accy = fmaxf(accy, 0.f); }
    *(float2*)(out + (size_t)i * DD + f) = make_float2(accx, accy);
}

// ---------------- fused Agg + mean-pool, node-sliced for occupancy ----------------
// part[sl][g][c] = (1/n_g) * sum_{i in slice sl of graph g} di*( di*g1[i][c] + sum_{s->i} ds*g1[s][c] )
// batch sorted -> graph g owns contiguous node range [lo,hi). Grid (NG, 2, PSLICE).
// 4096 blocks -> ~8 waves/SIMD so the 3-deep gather chain is TLP-hidden.
__global__ __launch_bounds__(256) void poolagg_kernel(const float* __restrict__ g1,
                                                      const int* __restrict__ batch, int bs,
                                                      const float* __restrict__ dis,
                                                      const int* __restrict__ rowptr,
                                                      const int* __restrict__ csrsrc,
                                                      float* __restrict__ part) {
    int g = blockIdx.x;
    int c = blockIdx.y * 256 + threadIdx.x;
    int sl = blockIdx.z;
    __shared__ int slo, shi;
    if (threadIdx.x == 0) {
        int lo = 0, hi = NN;
        while (lo < hi) { int m = (lo + hi) >> 1; if (batch[(size_t)m * bs] < g) lo = m + 1; else hi = m; }
        slo = lo;
        lo = slo; hi = NN;
        while (lo < hi) { int m = (lo + hi) >> 1; if (batch[(size_t)m * bs] < g + 1) lo = m + 1; else hi = m; }
        shi = lo;
    }
    __syncthreads();
    int lo = slo, hi = shi;
    int n = hi - lo;
    int a0 = lo + (int)(((long long)n * sl) / PSLICE);
    int a1 = lo + (int)(((long long)n * (sl + 1)) / PSLICE);
    float acc = 0.f;
    for (int i = a0; i < a1; ++i) {
        float di = dis[i];                              // wave-uniform broadcast
        float t = 0.f;
        int e0 = rowptr[i], e1 = rowptr[i + 1];
        for (int e = e0; e < e1; ++e) {
            int s = csrsrc[e];                          // broadcast
            t = fmaf(dis[s], g1[(size_t)s * DD + c], t);
        }
        float self = g1[(size_t)i * DD + c];
        acc = fmaf(di, fmaf(di, self, t), acc);
    }
    float inv = 1.0f / fmaxf((float)n, 1.0f);
    part[((size_t)sl * NG + g) * DD + c] = acc * inv;
}

// ---------------- final: out[128x512] = (sum_sl part[sl]) @ Wc + bc ----------------
__global__ __launch_bounds__(256) void final_kernel(const float* __restrict__ part,
                                                    const float* __restrict__ Wc,
                                                    const float* __restrict__ bc,
                                                    float* __restrict__ out) {
    __shared__ float p[DD];
    int g = blockIdx.x;
    int t = threadIdx.x;
    float s0 = 0.f, s1 = 0.f;
#pragma unroll
    for (int sl = 0; sl < PSLICE; ++sl) {
        s0 += part[((size_t)sl * NG + g) * DD + t];
        s1 += part[((size_t)sl * NG + g) * DD + t + 256];
    }
    p[t] = s0;
    p[t + 256] = s1;
    __syncthreads();
    int n0 = t, n1 = t + 256;
    float a0 = bc[n0], a1 = bc[n1];
    for (int k = 0; k < DD; ++k) {
        float pk = p[k];
        a0 = fmaf(pk, Wc[(size_t)k * DD + n0], a0);
        a1 = fmaf(pk, Wc[(size_t)k * DD + n1], a1);
    }
    out[(size_t)g * DD + n0] = a0;
    out[(size_t)g * DD + n1] = a1;
}

// ---------------- launch ----------------
extern "C" void kernel_launch(void* const* d_in, const int* in_sizes, int n_in,
                              void* d_out, int out_size, void* d_ws, size_t ws_size,
                              hipStream_t stream) {
    const float* x    = (const float*)d_in[0];
    const int*   ei   = (const int*)d_in[1];       // [2][160000], int32 or int64(lo,hi)
    const int*   batch= (const int*)d_in[2];
    const float* W1   = (const float*)d_in[3];
    const float* b1   = (const float*)d_in[4];
    const float* W2   = (const float*)d_in[5];
    const float* b2   = (const float*)d_in[6];
    const float* Wlin = (const float*)d_in[7];
    const float* blin = (const float*)d_in[8];
    float* out = (float*)d_out;

    // int64-vs-int32 layout detection (little-endian low word at stride 2)
    const int es = (in_sizes[1] == 2 * 2 * NE) ? 2 : 1;
    const int bs = (in_sizes[2] == 2 * NN) ? 2 : 1;
    const int* esrc = ei;
    const int* edst = ei + (size_t)NE * es;

    char* w = (char*)d_ws;
    auto alloc = [&](size_t bytes) { void* p = (void*)w; w += (bytes + 255) & ~(size_t)255; return p; };
    float* h      = (float*)alloc((size_t)NN * DD * 4);   // GEMM1 out; dead after agg ->
    float* part   = h;                                    //   reused as poolagg partials (16*128*512 = 4MB < 41MB)
    float* g      = (float*)alloc((size_t)NN * DD * 4);   // conv1 out (post-relu)
    float* W1s    = (float*)alloc((size_t)DD * DD * 4);
    float* Wc     = (float*)alloc((size_t)DD * DD * 4);   // W2 @ Wlin
    float* c1v    = (float*)alloc(DD * 4);
    float* bcv    = (float*)alloc(DD * 4);
    float* mu     = (float*)alloc(DD * 4);
    float* rstd   = (float*)alloc(DD * 4);
    float* stats  = (float*)alloc(2 * DD * 4);            // colsum | colsq
    float* dis    = (float*)alloc(NN * 4);
    int*   deg    = (int*)alloc(NN * 4);
    int*   rowptr = (int*)alloc((NN + 4) * 4);
    int*   cursor = (int*)alloc(NN * 4);
    int*   csrsrc = (int*)alloc(NE * 4);
    float* colsum = stats;
    float* colsq  = stats + DD;

    // folded tail weights: Wc = W2 @ Wlin, bc = b2 @ Wlin + blin (independent of x; overlaps stats)
    gemm_f32_kernel<<<dim3(4, 4), 256, 0, stream>>>(W2, Wlin, Wc, nullptr, DD);
    bc_kernel<<<512, 256, 0, stream>>>(Wlin, b2, blin, bcv);

    // scaler stats
    hipMemsetAsync(stats, 0, 2 * DD * 4, stream);
    colstats_kernel<<<dim3(2, 40), 256, 0, stream>>>(x, colsum, colsq);
    finalize_kernel<<<1, 512, 0, stream>>>(colsum, colsq, mu, rstd);
    scalew_kernel<<<1024, 256, 0, stream>>>(W1, rstd, W1s);
    c1_kernel<<<512, 256, 0, stream>>>(W1s, mu, c1v);

    // graph structure
    deginit_kernel<<<(NN + 255) / 256, 256, 0, stream>>>(deg);
    degcount_kernel<<<NE / 256, 256, 0, stream>>>(edst, deg, es);
    dis_kernel<<<(NN + 255) / 256, 256, 0, stream>>>(deg, dis);
    scan_kernel<<<1, 1024, 0, stream>>>(deg, rowptr, cursor);
    scatter_kernel<<<NE / 256, 256, 0, stream>>>(esrc, edst, cursor, csrsrc, es);

    dim3 ggrid((NN + BM - 1) / BM, DD / BN);
    // conv1: h = x @ W1s + c1 (scaler folded), then aggregate + b1 + relu -> g
    gemm_f32_kernel<<<ggrid, 256, 0, stream>>>(x, W1s, h, c1v, NN);
    agg_kernel<<<NN, 256, 0, stream>>>(h, g, dis, rowptr, csrsrc, b1, 1);
    // conv2 restructured: fused Agg+mean-pool from g, 16-way node-sliced (h is dead; part aliases it)
    poolagg_kernel<<<dim3(NG, 2, PSLICE), 256, 0, stream>>>(g, batch, bs, dis, rowptr, csrsrc, part);
    // tail: out = (sum of partials) @ Wc + bc
    final_kernel<<<NG, 256, 0, stream>>>(part, Wc, bcv, out);
}

// Round 9
// 456.823 us; speedup vs baseline: 1.2356x; 1.2356x over previous
//
#include <hip/hip_runtime.h>
#include <hip/hip_bf16.h>

// GCN forward: StandardScaler -> GCNConv(relu) -> GCNConv -> mean-pool -> Linear
// N=20000 nodes, E=160000 edges, D=512 all layers, G=128 graphs.
//
// Structure:
//  - scaler folded into GEMM1: xs@W1 = x@(rstd.W1) + c1
//  - GEMM1 runs on matrix cores via split-bf16 (AhBh + AhBl + AlBh), W1
//    pre-transposed+scaled+split once into [n][k] bf16 hi/lo
//  - GEMM2 eliminated algebraically: out = pool(Agg(g)) @ W2 @ Wlin + (b2@Wlin+blin),
//    applied as two tiny 128-row GEMMs after pooling
//  - pool(Agg(g)) fused, 16-way node-sliced for occupancy; partials alias dead h

#define NN 20000
#define NE 160000
#define DD 512
#define NG 128
#define PSLICE 16

typedef __attribute__((ext_vector_type(8))) short bf16x8;
typedef __attribute__((ext_vector_type(4))) float f32x4;

static __device__ __forceinline__ short f2bf(float f) {
    union { float f; unsigned u; } a; a.f = f;
    unsigned r = a.u + 0x7FFF + ((a.u >> 16) & 1);   // RNE
    return (short)(r >> 16);
}
static __device__ __forceinline__ float bf2f(short s) {
    union { unsigned u; float f; } a; a.u = ((unsigned)(unsigned short)s) << 16;
    return a.f;
}

// ---------------- column stats (mean / rstd) ----------------
__global__ __launch_bounds__(256) void colstats_kernel(const float* __restrict__ x,
                                                       float* __restrict__ colsum,
                                                       float* __restrict__ colsq) {
    int c = blockIdx.x * 256 + threadIdx.x;          // 2 x-blocks cover 512 cols
    int r0 = blockIdx.y * 100;                       // 200 y-blocks cover 20000 rows
    float s = 0.f, sq = 0.f;
    for (int r = r0; r < r0 + 100; ++r) {
        float v = x[(size_t)r * DD + c];
        s += v;
        sq = fmaf(v, v, sq);
    }
    atomicAdd(&colsum[c], s);
    atomicAdd(&colsq[c], sq);
}

__global__ void finalize_kernel(const float* __restrict__ colsum, const float* __restrict__ colsq,
                                float* __restrict__ rstd, float* __restrict__ murs) {
    int c = threadIdx.x;                              // 512 threads
    float m = colsum[c] * (1.0f / NN);
    float var = colsq[c] * (1.0f / NN) - m * m;
    float sd = sqrtf(fmaxf(var, 0.0f));
    float rs = (sd > 0.0f) ? (1.0f / sd) : 1.0f;      // ref: divide by where(sd>0, sd, 1)
    rstd[c] = rs;
    murs[c] = m * rs;
}

// W^T scale + bf16 split: Wh/Wl[n][k] = split(rstd[k] * W1[k][n]); 32x32 LDS tiles
__global__ __launch_bounds__(256) void wsplit_kernel(const float* __restrict__ W1,
                                                     const float* __restrict__ rstd,
                                                     short* __restrict__ Wh,
                                                     short* __restrict__ Wl) {
    __shared__ float t[32][33];
    int bk = blockIdx.x * 32, bn = blockIdx.y * 32;
    int r = threadIdx.x >> 5, c = threadIdx.x & 31;
#pragma unroll
    for (int i = 0; i < 4; ++i) {
        int rr = r + i * 8;
        t[rr][c] = W1[(size_t)(bk + rr) * DD + bn + c] * rstd[bk + rr];
    }
    __syncthreads();
#pragma unroll
    for (int i = 0; i < 4; ++i) {
        int rr = r + i * 8;                           // output n-row
        float v = t[c][rr];                           // transposed read
        short h = f2bf(v);
        short l = f2bf(v - bf2f(h));
        Wh[(size_t)(bn + rr) * DD + bk + c] = h;
        Wl[(size_t)(bn + rr) * DD + bk + c] = l;
    }
}

// c1[n] = -sum_k murs[k] * W1[k][n]
__global__ __launch_bounds__(256) void c1_kernel(const float* __restrict__ W1,
                                                 const float* __restrict__ murs,
                                                 float* __restrict__ c1v) {
    int n = blockIdx.x;
    float s = 0.f;
    for (int k = threadIdx.x; k < DD; k += 256)
        s = fmaf(murs[k], W1[(size_t)k * DD + n], s);
    __shared__ float red[256];
    red[threadIdx.x] = s;
    __syncthreads();
    for (int off = 128; off > 0; off >>= 1) {
        if (threadIdx.x < off) red[threadIdx.x] += red[threadIdx.x + off];
        __syncthreads();
    }
    if (threadIdx.x == 0) c1v[n] = -red[0];
}

// ---------------- graph structure (CSR by destination) ----------------
__global__ void deginit_kernel(int* __restrict__ deg) {
    int i = blockIdx.x * 256 + threadIdx.x;
    if (i < NN) deg[i] = 1;                           // self-loop contributes 1
}

__global__ void degcount_kernel(const int* __restrict__ dst, int* __restrict__ deg, int es) {
    int e = blockIdx.x * 256 + threadIdx.x;
    if (e < NE) {
        int d = dst[(size_t)e * es];
        if ((unsigned)d < (unsigned)NN) atomicAdd(&deg[d], 1);
    }
}

__global__ void dis_kernel(const int* __restrict__ deg, float* __restrict__ dis) {
    int i = blockIdx.x * 256 + threadIdx.x;
    if (i < NN) dis[i] = rsqrtf((float)deg[i]);       // deg >= 1 always
}

// exclusive scan of indeg (deg-1); writes rowptr[0..20000] and cursor copy
__global__ __launch_bounds__(1024) void scan_kernel(const int* __restrict__ deg,
                                                    int* __restrict__ rowptr,
                                                    int* __restrict__ cursor) {
    const int PER = 20;                               // 1024*20 = 20480 >= 20001
    __shared__ int sums[1024];
    int t = threadIdx.x;
    int base = t * PER;
    int local[PER];
    int s = 0;
#pragma unroll
    for (int j = 0; j < PER; ++j) {
        int idx = base + j;
        int v = (idx < NN) ? (deg[idx] - 1) : 0;
        local[j] = s;
        s += v;
    }
    sums[t] = s;
    __syncthreads();
    for (int off = 1; off < 1024; off <<= 1) {
        int v = (t >= off) ? sums[t - off] : 0;
        __syncthreads();
        sums[t] += v;
        __syncthreads();
    }
    int prefix = (t == 0) ? 0 : sums[t - 1];
#pragma unroll
    for (int j = 0; j < PER; ++j) {
        int idx = base + j;
        if (idx <= NN) {
            int val = prefix + local[j];
            rowptr[idx] = val;
            if (idx < NN) cursor[idx] = val;
        }
    }
}

__global__ void scatter_kernel(const int* __restrict__ src, const int* __restrict__ dst,
                               int* __restrict__ cursor, int* __restrict__ csrsrc, int es) {
    int e = blockIdx.x * 256 + threadIdx.x;
    if (e < NE) {
        int d = dst[(size_t)e * es];
        int sN = src[(size_t)e * es];
        if ((unsigned)d < (unsigned)NN && (unsigned)sN < (unsigned)NN) {
            int slot = atomicAdd(&cursor[d], 1);
            csrsrc[slot] = sN;
        }
    }
}

// ---------------- split-bf16 MFMA GEMM: C[M x 512] = A[M x 512] @ W + bias ----------------
// W pre-split: Bh/Bl[n][k] bf16. A split in-kernel. 3 MFMA terms: AhBh + AhBl + AlBh.
// 128x128 tile, BK=32, 4 waves each computing 64x64 via 4x4 frags of 16x16x32.
__global__ __launch_bounds__(256) void gemm_mfma_kernel(const float* __restrict__ A,
                                                        const short* __restrict__ Bh,
                                                        const short* __restrict__ Bl,
                                                        float* __restrict__ C,
                                                        const float* __restrict__ bias,
                                                        int M) {
    __shared__ __attribute__((aligned(16))) short Ah[128][40];
    __shared__ __attribute__((aligned(16))) short Al[128][40];
    __shared__ __attribute__((aligned(16))) short Bsh[128][40];
    __shared__ __attribute__((aligned(16))) short Bsl[128][40];
    int tid = threadIdx.x;
    int wave = tid >> 6, lane = tid & 63;
    int wm = (wave >> 1) * 64, wn = (wave & 1) * 64;
    int rowBase = blockIdx.x * 128, colBase = blockIdx.y * 128;

    f32x4 acc[4][4];
#pragma unroll
    for (int i = 0; i < 4; ++i)
#pragma unroll
        for (int j = 0; j < 4; ++j) acc[i][j] = (f32x4){0.f, 0.f, 0.f, 0.f};

    int fr = lane & 15, kq = (lane >> 4) * 8;

    for (int k0 = 0; k0 < DD; k0 += 32) {
        // stage A tile (128 x 32 fp32), split to bf16 hi/lo
#pragma unroll
        for (int i = 0; i < 4; ++i) {
            int lin = tid + i * 256;                  // 0..1023 float4 slots
            int r = lin >> 3, kc = (lin & 7) * 4;
            float4 v = make_float4(0.f, 0.f, 0.f, 0.f);
            int gr = rowBase + r;
            if (gr < M) v = *(const float4*)(A + (size_t)gr * DD + k0 + kc);
            short h0 = f2bf(v.x), h1 = f2bf(v.y), h2 = f2bf(v.z), h3 = f2bf(v.w);
            short l0 = f2bf(v.x - bf2f(h0)), l1 = f2bf(v.y - bf2f(h1));
            short l2 = f2bf(v.z - bf2f(h2)), l3 = f2bf(v.w - bf2f(h3));
            *(short4*)&Ah[r][kc] = make_short4(h0, h1, h2, h3);
            *(short4*)&Al[r][kc] = make_short4(l0, l1, l2, l3);
        }
        // stage B tiles (128 n x 32 k bf16, already [n][k])
#pragma unroll
        for (int i = 0; i < 2; ++i) {
            int lin = tid + i * 256;                  // 0..511 uint4 slots
            int n = lin >> 2, k8 = (lin & 3) * 8;
            *(uint4*)&Bsh[n][k8] = *(const uint4*)(Bh + (size_t)(colBase + n) * DD + k0 + k8);
            *(uint4*)&Bsl[n][k8] = *(const uint4*)(Bl + (size_t)(colBase + n) * DD + k0 + k8);
        }
        __syncthreads();

        bf16x8 ah[4], al[4], bh[4], bl[4];
#pragma unroll
        for (int mi = 0; mi < 4; ++mi) {
            ah[mi] = *(const bf16x8*)&Ah[wm + mi * 16 + fr][kq];
            al[mi] = *(const bf16x8*)&Al[wm + mi * 16 + fr][kq];
        }
#pragma unroll
        for (int ni = 0; ni < 4; ++ni) {
            bh[ni] = *(const bf16x8*)&Bsh[wn + ni * 16 + fr][kq];
            bl[ni] = *(const bf16x8*)&Bsl[wn + ni * 16 + fr][kq];
        }
#pragma unroll
        for (int mi = 0; mi < 4; ++mi)
#pragma unroll
            for (int ni = 0; ni < 4; ++ni) {
                acc[mi][ni] = __builtin_amdgcn_mfma_f32_16x16x32_bf16(ah[mi], bh[ni], acc[mi][ni], 0, 0, 0);
                acc[mi][ni] = __builtin_amdgcn_mfma_f32_16x16x32_bf16(ah[mi], bl[ni], acc[mi][ni], 0, 0, 0);
                acc[mi][ni] = __builtin_amdgcn_mfma_f32_16x16x32_bf16(al[mi], bh[ni], acc[mi][ni], 0, 0, 0);
            }
        __syncthreads();
    }

    // epilogue: C/D layout col = lane&15, row = (lane>>4)*4 + reg
#pragma unroll
    for (int mi = 0; mi < 4; ++mi) {
#pragma unroll
        for (int ni = 0; ni < 4; ++ni) {
            int col = colBase + wn + ni * 16 + (lane & 15);
            int row0 = rowBase + wm + mi * 16 + (lane >> 4) * 4;
            float b = bias[col];
#pragma unroll
            for (int r = 0; r < 4; ++r) {
                int row = row0 + r;
                if (row < M) C[(size_t)row * DD + col] = acc[mi][ni][r] + b;
            }
        }
    }
}

// ---------------- edge aggregation: out[i] = di*(di*h[i] + sum_e dis[s]*h[s]) + b [relu] ----
__global__ __launch_bounds__(256) void agg_kernel(const float* __restrict__ h,
                                                  float* __restrict__ out,
                                                  const float* __restrict__ dis,
                                                  const int* __restrict__ rowptr,
                                                  const int* __restrict__ csrsrc,
                                                  const float* __restrict__ bias,
                                                  int relu) {
    int i = blockIdx.x;
    int f = threadIdx.x * 2;
    float di = dis[i];
    float2 v = *(const float2*)(h + (size_t)i * DD + f);
    float accx = di * v.x, accy = di * v.y;
    int e0 = rowptr[i], e1 = rowptr[i + 1];
    if (e0 < e1) {
        int s = csrsrc[e0];
        float ds = dis[s];
        for (int e = e0; e < e1; ++e) {
            int   sn = 0;
            float dn = 0.f;
            if (e + 1 < e1) { sn = csrsrc[e + 1]; dn = dis[sn]; }   // prefetch next
            float2 hv = *(const float2*)(h + (size_t)s * DD + f);
            accx = fmaf(ds, hv.x, accx);
            accy = fmaf(ds, hv.y, accy);
            s = sn; ds = dn;
        }
    }
    accx = fmaf(di, accx, bias[f]);
    accy = fmaf(di, accy, bias[f + 1]);
    if (relu) { accx = fmaxf(accx, 0.f); accy = fmaxf(accy, 0.f); }
    *(float2*)(out + (size_t)i * DD + f) = make_float2(accx, accy);
}

// ---------------- fused Agg + mean-pool, node-sliced for occupancy ----------------
__global__ __launch_bounds__(256) void poolagg_kernel(const float* __restrict__ g1,
                                                      const int* __restrict__ batch, int bs,
                                                      const float* __restrict__ dis,
                                                      const int* __restrict__ rowptr,
                                                      const int* __restrict__ csrsrc,
                                                      float* __restrict__ part) {
    int g = blockIdx.x;
    int c = blockIdx.y * 256 + threadIdx.x;
    int sl = blockIdx.z;
    __shared__ int slo, shi;
    if (threadIdx.x == 0) {
        int lo = 0, hi = NN;
        while (lo < hi) { int m = (lo + hi) >> 1; if (batch[(size_t)m * bs] < g) lo = m + 1; else hi = m; }
        slo = lo;
        lo = slo; hi = NN;
        while (lo < hi) { int m = (lo + hi) >> 1; if (batch[(size_t)m * bs] < g + 1) lo = m + 1; else hi = m; }
        shi = lo;
    }
    __syncthreads();
    int lo = slo, hi = shi;
    int n = hi - lo;
    int a0 = lo + (int)(((long long)n * sl) / PSLICE);
    int a1 = lo + (int)(((long long)n * (sl + 1)) / PSLICE);
    float acc = 0.f;
    for (int i = a0; i < a1; ++i) {
        float di = dis[i];
        float t = 0.f;
        int e0 = rowptr[i], e1 = rowptr[i + 1];
        for (int e = e0; e < e1; ++e) {
            int s = csrsrc[e];
            t = fmaf(dis[s], g1[(size_t)s * DD + c], t);
        }
        float self = g1[(size_t)i * DD + c];
        acc = fmaf(di, fmaf(di, self, t), acc);
    }
    float inv = 1.0f / fmaxf((float)n, 1.0f);
    part[((size_t)sl * NG + g) * DD + c] = acc * inv;
}

// ---------------- small dense tail: dst[128x512] = (sum_sl src[sl]) @ W + bias ----------------
__global__ __launch_bounds__(256) void final_kernel(const float* __restrict__ src, int nslice,
                                                    const float* __restrict__ W,
                                                    const float* __restrict__ bias,
                                                    float* __restrict__ dst) {
    __shared__ float p[DD];
    int g = blockIdx.x;
    int t = threadIdx.x;
    float s0 = 0.f, s1 = 0.f;
    for (int sl = 0; sl < nslice; ++sl) {
        s0 += src[((size_t)sl * NG + g) * DD + t];
        s1 += src[((size_t)sl * NG + g) * DD + t + 256];
    }
    p[t] = s0;
    p[t + 256] = s1;
    __syncthreads();
    float a0 = bias[t], a1 = bias[t + 256];
    for (int k = 0; k < DD; ++k) {
        float pk = p[k];
        a0 = fmaf(pk, W[(size_t)k * DD + t], a0);
        a1 = fmaf(pk, W[(size_t)k * DD + t + 256], a1);
    }
    dst[(size_t)g * DD + t] = a0;
    dst[(size_t)g * DD + t + 256] = a1;
}

// ---------------- launch ----------------
extern "C" void kernel_launch(void* const* d_in, const int* in_sizes, int n_in,
                              void* d_out, int out_size, void* d_ws, size_t ws_size,
                              hipStream_t stream) {
    const float* x    = (const float*)d_in[0];
    const int*   ei   = (const int*)d_in[1];       // [2][160000], int32 or int64(lo,hi)
    const int*   batch= (const int*)d_in[2];
    const float* W1   = (const float*)d_in[3];
    const float* b1   = (const float*)d_in[4];
    const float* W2   = (const float*)d_in[5];
    const float* b2   = (const float*)d_in[6];
    const float* Wlin = (const float*)d_in[7];
    const float* blin = (const float*)d_in[8];
    float* out = (float*)d_out;

    // int64-vs-int32 layout detection (little-endian low word at stride 2)
    const int es = (in_sizes[1] == 2 * 2 * NE) ? 2 : 1;
    const int bs = (in_sizes[2] == 2 * NN) ? 2 : 1;
    const int* esrc = ei;
    const int* edst = ei + (size_t)NE * es;

    char* w = (char*)d_ws;
    auto alloc = [&](size_t bytes) { void* p = (void*)w; w += (bytes + 255) & ~(size_t)255; return p; };
    float* h      = (float*)alloc((size_t)NN * DD * 4);   // GEMM1 out; dead after agg ->
    float* part   = h;                                    //   reused as poolagg partials (4 MB < 41 MB)
    float* g      = (float*)alloc((size_t)NN * DD * 4);   // conv1 out (post-relu)
    short* W1h    = (short*)alloc((size_t)DD * DD * 2);   // W1^T scaled, bf16 hi
    short* W1l    = (short*)alloc((size_t)DD * DD * 2);   // bf16 lo
    float* tbuf   = (float*)alloc((size_t)NG * DD * 4);   // pooled@W2+b2
    float* c1v    = (float*)alloc(DD * 4);
    float* rstd   = (float*)alloc(DD * 4);
    float* murs   = (float*)alloc(DD * 4);
    float* stats  = (float*)alloc(2 * DD * 4);            // colsum | colsq
    float* dis    = (float*)alloc(NN * 4);
    int*   deg    = (int*)alloc(NN * 4);
    int*   rowptr = (int*)alloc((NN + 4) * 4);
    int*   cursor = (int*)alloc(NN * 4);
    int*   csrsrc = (int*)alloc(NE * 4);
    float* colsum = stats;
    float* colsq  = stats + DD;

    // scaler stats -> rstd, mu*rstd
    hipMemsetAsync(stats, 0, 2 * DD * 4, stream);
    colstats_kernel<<<dim3(2, 200), 256, 0, stream>>>(x, colsum, colsq);
    finalize_kernel<<<1, 512, 0, stream>>>(colsum, colsq, rstd, murs);
    // W1 -> transposed scaled bf16 split, and folded bias c1
    wsplit_kernel<<<dim3(16, 16), 256, 0, stream>>>(W1, rstd, W1h, W1l);
    c1_kernel<<<512, 256, 0, stream>>>(W1, murs, c1v);

    // graph structure
    deginit_kernel<<<(NN + 255) / 256, 256, 0, stream>>>(deg);
    degcount_kernel<<<NE / 256, 256, 0, stream>>>(edst, deg, es);
    dis_kernel<<<(NN + 255) / 256, 256, 0, stream>>>(deg, dis);
    scan_kernel<<<1, 1024, 0, stream>>>(deg, rowptr, cursor);
    scatter_kernel<<<NE / 256, 256, 0, stream>>>(esrc, edst, cursor, csrsrc, es);

    // conv1: h = x @ W1s + c1 via split-bf16 MFMA, then aggregate + b1 + relu -> g
    gemm_mfma_kernel<<<dim3((NN + 127) / 128, DD / 128), 256, 0, stream>>>(x, W1h, W1l, h, c1v, NN);
    agg_kernel<<<NN, 256, 0, stream>>>(h, g, dis, rowptr, csrsrc, b1, 1);
    // conv2 restructured: fused Agg+mean-pool from g, 16-way node-sliced
    poolagg_kernel<<<dim3(NG, 2, PSLICE), 256, 0, stream>>>(g, batch, bs, dis, rowptr, csrsrc, part);
    // tail: out = ((pooled @ W2 + b2) @ Wlin + blin)
    final_kernel<<<NG, 256, 0, stream>>>(part, PSLICE, W2, b2, tbuf);
    final_kernel<<<NG, 256, 0, stream>>>(tbuf, 1, Wlin, blin, out);
}

// Round 11
// 417.824 us; speedup vs baseline: 1.3509x; 1.0933x over previous
//
#include <hip/hip_runtime.h>
#include <hip/hip_bf16.h>

// GCN forward: StandardScaler -> GCNConv(relu) -> GCNConv -> mean-pool -> Linear
// N=20000 nodes, E=160000 edges, D=512 all layers, G=128 graphs.
//
// Structure:
//  - xs = (x-mu)*rstd pre-split ONCE to bf16 hi/lo (xsplit); GEMM1 = xs@W1 on
//    matrix cores, 3-term split-bf16 (AhBh + AhBl + AlBh), reg-staged pipeline
//  - GEMM2 eliminated algebraically: out = pool(Agg(g)) @ W2 @ Wlin + (b2@Wlin+blin)
//  - pool(Agg(g)) fused, 16-way node-sliced; partials alias dead h
//  - xh/xl alias g (dead until agg writes it, after gemm consumed xh/xl)

#define NN 20000
#define NE 160000
#define DD 512
#define NG 128
#define PSLICE 16

typedef __attribute__((ext_vector_type(8))) short bf16x8;
typedef __attribute__((ext_vector_type(4))) float f32x4;

static __device__ __forceinline__ short f2bf(float f) {
    union { float f; unsigned u; } a; a.f = f;
    unsigned r = a.u + 0x7FFF + ((a.u >> 16) & 1);   // RNE
    return (short)(r >> 16);
}
static __device__ __forceinline__ float bf2f(short s) {
    union { unsigned u; float f; } a; a.u = ((unsigned)(unsigned short)s) << 16;
    return a.f;
}

// ---------------- column stats (mean / rstd) ----------------
__global__ __launch_bounds__(256) void colstats_kernel(const float* __restrict__ x,
                                                       float* __restrict__ colsum,
                                                       float* __restrict__ colsq) {
    int c = blockIdx.x * 256 + threadIdx.x;          // 2 x-blocks cover 512 cols
    int r0 = blockIdx.y * 100;                       // 200 y-blocks cover 20000 rows
    float s = 0.f, sq = 0.f;
    for (int r = r0; r < r0 + 100; ++r) {
        float v = x[(size_t)r * DD + c];
        s += v;
        sq = fmaf(v, v, sq);
    }
    atomicAdd(&colsum[c], s);
    atomicAdd(&colsq[c], sq);
}

__global__ void finalize_kernel(const float* __restrict__ colsum, const float* __restrict__ colsq,
                                float* __restrict__ rstd, float* __restrict__ murs) {
    int c = threadIdx.x;                              // 512 threads
    float m = colsum[c] * (1.0f / NN);
    float var = colsq[c] * (1.0f / NN) - m * m;
    float sd = sqrtf(fmaxf(var, 0.0f));
    float rs = (sd > 0.0f) ? (1.0f / sd) : 1.0f;      // ref: divide by where(sd>0, sd, 1)
    rstd[c] = rs;
    murs[c] = m * rs;
}

// xs = (x - mu) * rstd = x*rstd - murs, split to bf16 hi/lo. One float4 per thread.
__global__ __launch_bounds__(256) void xsplit_kernel(const float* __restrict__ x,
                                                     const float* __restrict__ rstd,
                                                     const float* __restrict__ murs,
                                                     short* __restrict__ xh,
                                                     short* __restrict__ xl) {
    int idx = blockIdx.x * 256 + threadIdx.x;        // 10000 blocks * 256 = 2,560,000 float4
    int c4 = (idx & 127) * 4;                        // 128 float4 per row
    float4 v = *(const float4*)(x + (size_t)idx * 4);
    float4 rs = *(const float4*)(rstd + c4);
    float4 ms = *(const float4*)(murs + c4);
    float s0 = fmaf(v.x, rs.x, -ms.x), s1 = fmaf(v.y, rs.y, -ms.y);
    float s2 = fmaf(v.z, rs.z, -ms.z), s3 = fmaf(v.w, rs.w, -ms.w);
    short h0 = f2bf(s0), h1 = f2bf(s1), h2 = f2bf(s2), h3 = f2bf(s3);
    *(short4*)(xh + (size_t)idx * 4) = make_short4(h0, h1, h2, h3);
    *(short4*)(xl + (size_t)idx * 4) =
        make_short4(f2bf(s0 - bf2f(h0)), f2bf(s1 - bf2f(h1)),
                    f2bf(s2 - bf2f(h2)), f2bf(s3 - bf2f(h3)));
}

// W^T bf16 split (unscaled): Wh/Wl[n][k] = split(W1[k][n]); 32x32 LDS tiles
__global__ __launch_bounds__(256) void wsplit_kernel(const float* __restrict__ W1,
                                                     short* __restrict__ Wh,
                                                     short* __restrict__ Wl) {
    __shared__ float t[32][33];
    int bk = blockIdx.x * 32, bn = blockIdx.y * 32;
    int r = threadIdx.x >> 5, c = threadIdx.x & 31;
#pragma unroll
    for (int i = 0; i < 4; ++i) {
        int rr = r + i * 8;
        t[rr][c] = W1[(size_t)(bk + rr) * DD + bn + c];
    }
    __syncthreads();
#pragma unroll
    for (int i = 0; i < 4; ++i) {
        int rr = r + i * 8;                           // output n-row
        float v = t[c][rr];                           // transposed read
        short h = f2bf(v);
        short l = f2bf(v - bf2f(h));
        Wh[(size_t)(bn + rr) * DD + bk + c] = h;
        Wl[(size_t)(bn + rr) * DD + bk + c] = l;
    }
}

// ---------------- graph structure (CSR by destination) ----------------
__global__ void deginit_kernel(int* __restrict__ deg) {
    int i = blockIdx.x * 256 + threadIdx.x;
    if (i < NN) deg[i] = 1;                           // self-loop contributes 1
}

__global__ void degcount_kernel(const int* __restrict__ dst, int* __restrict__ deg, int es) {
    int e = blockIdx.x * 256 + threadIdx.x;
    if (e < NE) {
        int d = dst[(size_t)e * es];
        if ((unsigned)d < (unsigned)NN) atomicAdd(&deg[d], 1);
    }
}

__global__ void dis_kernel(const int* __restrict__ deg, float* __restrict__ dis) {
    int i = blockIdx.x * 256 + threadIdx.x;
    if (i < NN) dis[i] = rsqrtf((float)deg[i]);       // deg >= 1 always
}

// exclusive scan of indeg (deg-1); writes rowptr[0..20000] and cursor copy
__global__ __launch_bounds__(1024) void scan_kernel(const int* __restrict__ deg,
                                                    int* __restrict__ rowptr,
                                                    int* __restrict__ cursor) {
    const int PER = 20;                               // 1024*20 = 20480 >= 20001
    __shared__ int sums[1024];
    int t = threadIdx.x;
    int base = t * PER;
    int local[PER];
    int s = 0;
#pragma unroll
    for (int j = 0; j < PER; ++j) {
        int idx = base + j;
        int v = (idx < NN) ? (deg[idx] - 1) : 0;
        local[j] = s;
        s += v;
    }
    sums[t] = s;
    __syncthreads();
    for (int off = 1; off < 1024; off <<= 1) {
        int v = (t >= off) ? sums[t - off] : 0;
        __syncthreads();
        sums[t] += v;
        __syncthreads();
    }
    int prefix = (t == 0) ? 0 : sums[t - 1];
#pragma unroll
    for (int j = 0; j < PER; ++j) {
        int idx = base + j;
        if (idx <= NN) {
            int val = prefix + local[j];
            rowptr[idx] = val;
            if (idx < NN) cursor[idx] = val;
        }
    }
}

__global__ void scatter_kernel(const int* __restrict__ src, const int* __restrict__ dst,
                               int* __restrict__ cursor, int* __restrict__ csrsrc, int es) {
    int e = blockIdx.x * 256 + threadIdx.x;
    if (e < NE) {
        int d = dst[(size_t)e * es];
        int sN = src[(size_t)e * es];
        if ((unsigned)d < (unsigned)NN && (unsigned)sN < (unsigned)NN) {
            int slot = atomicAdd(&cursor[d], 1);
            csrsrc[slot] = sN;
        }
    }
}

// ---------------- split-bf16 MFMA GEMM: C[M x 512] = A @ W^T  (A,W pre-split bf16) ------------
// Reg-staged pipeline: load K-tile t+1 into regs while computing tile t.
// 128x128 tile, BK=32, 4 waves each computing 64x64 via 4x4 frags of 16x16x32.
__global__ __launch_bounds__(256) void gemm_mfma_kernel(const short* __restrict__ Ah_g,
                                                        const short* __restrict__ Al_g,
                                                        const short* __restrict__ Bh_g,
                                                        const short* __restrict__ Bl_g,
                                                        float* __restrict__ C,
                                                        int M) {
    __shared__ __attribute__((aligned(16))) short sAh[128][40];
    __shared__ __attribute__((aligned(16))) short sAl[128][40];
    __shared__ __attribute__((aligned(16))) short sBh[128][40];
    __shared__ __attribute__((aligned(16))) short sBl[128][40];
    int tid = threadIdx.x;
    int wave = tid >> 6, lane = tid & 63;
    int wm = (wave >> 1) * 64, wn = (wave & 1) * 64;
    int rowBase = blockIdx.x * 128, colBase = blockIdx.y * 128;
    int fr = lane & 15, kq = (lane >> 4) * 8;

    // staging slot geometry: two 16B slots per thread per buffer
    int s0 = tid, s1 = tid + 256;
    int r0 = s0 >> 2, k80 = (s0 & 3) * 8;
    int r1 = s1 >> 2, k81 = (s1 & 3) * 8;
    int ga0 = rowBase + r0, ga1 = rowBase + r1;       // A rows (guard vs M)
    int gb0 = colBase + r0, gb1 = colBase + r1;       // B n-rows (always < 512)
    const bool av0 = ga0 < M, av1 = ga1 < M;

    f32x4 acc[4][4];
#pragma unroll
    for (int i = 0; i < 4; ++i)
#pragma unroll
        for (int j = 0; j < 4; ++j) acc[i][j] = (f32x4){0.f, 0.f, 0.f, 0.f};

    const bf16x8 z8 = {0, 0, 0, 0, 0, 0, 0, 0};
    bf16x8 rAh0, rAh1, rAl0, rAl1, rBh0, rBh1, rBl0, rBl1;

#define GLOAD(KK)                                                                      \
    do {                                                                               \
        rAh0 = av0 ? *(const bf16x8*)(Ah_g + (size_t)ga0 * DD + (KK) + k80) : z8;      \
        rAl0 = av0 ? *(const bf16x8*)(Al_g + (size_t)ga0 * DD + (KK) + k80) : z8;      \
        rAh1 = av1 ? *(const bf16x8*)(Ah_g + (size_t)ga1 * DD + (KK) + k81) : z8;      \
        rAl1 = av1 ? *(const bf16x8*)(Al_g + (size_t)ga1 * DD + (KK) + k81) : z8;      \
        rBh0 = *(const bf16x8*)(Bh_g + (size_t)gb0 * DD + (KK) + k80);                 \
        rBl0 = *(const bf16x8*)(Bl_g + (size_t)gb0 * DD + (KK) + k80);                 \
        rBh1 = *(const bf16x8*)(Bh_g + (size_t)gb1 * DD + (KK) + k81);                 \
        rBl1 = *(const bf16x8*)(Bl_g + (size_t)gb1 * DD + (KK) + k81);                 \
    } while (0)

    GLOAD(0);
    for (int step = 0; step < 16; ++step) {
        // commit staged regs to LDS
        *(bf16x8*)&sAh[r0][k80] = rAh0;  *(bf16x8*)&sAl[r0][k80] = rAl0;
        *(bf16x8*)&sAh[r1][k81] = rAh1;  *(bf16x8*)&sAl[r1][k81] = rAl1;
        *(bf16x8*)&sBh[r0][k80] = rBh0;  *(bf16x8*)&sBl[r0][k80] = rBl0;
        *(bf16x8*)&sBh[r1][k81] = rBh1;  *(bf16x8*)&sBl[r1][k81] = rBl1;
        __syncthreads();
        // prefetch next K-tile into regs; latency hides under frag reads + MFMA
        if (step < 15) GLOAD((step + 1) * 32);

        bf16x8 fah[4], fal[4], fbh[4], fbl[4];
#pragma unroll
        for (int mi = 0; mi < 4; ++mi) {
            fah[mi] = *(const bf16x8*)&sAh[wm + mi * 16 + fr][kq];
            fal[mi] = *(const bf16x8*)&sAl[wm + mi * 16 + fr][kq];
        }
#pragma unroll
        for (int ni = 0; ni < 4; ++ni) {
            fbh[ni] = *(const bf16x8*)&sBh[wn + ni * 16 + fr][kq];
            fbl[ni] = *(const bf16x8*)&sBl[wn + ni * 16 + fr][kq];
        }
#pragma unroll
        for (int mi = 0; mi < 4; ++mi)
#pragma unroll
            for (int ni = 0; ni < 4; ++ni) {
                acc[mi][ni] = __builtin_amdgcn_mfma_f32_16x16x32_bf16(fah[mi], fbh[ni], acc[mi][ni], 0, 0, 0);
                acc[mi][ni] = __builtin_amdgcn_mfma_f32_16x16x32_bf16(fah[mi], fbl[ni], acc[mi][ni], 0, 0, 0);
                acc[mi][ni] = __builtin_amdgcn_mfma_f32_16x16x32_bf16(fal[mi], fbh[ni], acc[mi][ni], 0, 0, 0);
            }
        __syncthreads();
    }
#undef GLOAD

    // epilogue: C/D layout col = lane&15, row = (lane>>4)*4 + reg
#pragma unroll
    for (int mi = 0; mi < 4; ++mi)
#pragma unroll
        for (int ni = 0; ni < 4; ++ni) {
            int col = colBase + wn + ni * 16 + fr;
            int row0 = rowBase + wm + mi * 16 + (lane >> 4) * 4;
#pragma unroll
            for (int r = 0; r < 4; ++r) {
                int row = row0 + r;
                if (row < M) C[(size_t)row * DD + col] = acc[mi][ni][r];
            }
        }
}

// ---------------- edge aggregation: out[i] = di*(di*h[i] + sum_e dis[s]*h[s]) + b [relu] ----
__global__ __launch_bounds__(256) void agg_kernel(const float* __restrict__ h,
                                                  float* __restrict__ out,
                                                  const float* __restrict__ dis,
                                                  const int* __restrict__ rowptr,
                                                  const int* __restrict__ csrsrc,
                                                  const float* __restrict__ bias,
                                                  int relu) {
    int i = blockIdx.x;
    int f = threadIdx.x * 2;
    float di = dis[i];
    float2 v = *(const float2*)(h + (size_t)i * DD + f);
    float accx = di * v.x, accy = di * v.y;
    int e0 = rowptr[i], e1 = rowptr[i + 1];
    if (e0 < e1) {
        int s = csrsrc[e0];
        float ds = dis[s];
        for (int e = e0; e < e1; ++e) {
            int   sn = 0;
            float dn = 0.f;
            if (e + 1 < e1) { sn = csrsrc[e + 1]; dn = dis[sn]; }   // prefetch next
            float2 hv = *(const float2*)(h + (size_t)s * DD + f);
            accx = fmaf(ds, hv.x, accx);
            accy = fmaf(ds, hv.y, accy);
            s = sn; ds = dn;
        }
    }
    accx = fmaf(di, accx, bias[f]);
    accy = fmaf(di, accy, bias[f + 1]);
    if (relu) { accx = fmaxf(accx, 0.f); accy = fmaxf(accy, 0.f); }
    *(float2*)(out + (size_t)i * DD + f) = make_float2(accx, accy);
}

// ---------------- fused Agg + mean-pool, node-sliced for occupancy ----------------
__global__ __launch_bounds__(256) void poolagg_kernel(const float* __restrict__ g1,
                                                      const int* __restrict__ batch, int bs,
                                                      const float* __restrict__ dis,
                                                      const int* __restrict__ rowptr,
                                                      const int* __restrict__ csrsrc,
                                                      float* __restrict__ part) {
    int g = blockIdx.x;
    int c = blockIdx.y * 256 + threadIdx.x;
    int sl = blockIdx.z;
    __shared__ int slo, shi;
    if (threadIdx.x == 0) {
        int lo = 0, hi = NN;
        while (lo < hi) { int m = (lo + hi) >> 1; if (batch[(size_t)m * bs] < g) lo = m + 1; else hi = m; }
        slo = lo;
        lo = slo; hi = NN;
        while (lo < hi) { int m = (lo + hi) >> 1; if (batch[(size_t)m * bs] < g + 1) lo = m + 1; else hi = m; }
        shi = lo;
    }
    __syncthreads();
    int lo = slo, hi = shi;
    int n = hi - lo;
    int a0 = lo + (int)(((long long)n * sl) / PSLICE);
    int a1 = lo + (int)(((long long)n * (sl + 1)) / PSLICE);
    float acc = 0.f;
    for (int i = a0; i < a1; ++i) {
        float di = dis[i];
        float t = 0.f;
        int e0 = rowptr[i], e1 = rowptr[i + 1];
        for (int e = e0; e < e1; ++e) {
            int s = csrsrc[e];
            t = fmaf(dis[s], g1[(size_t)s * DD + c], t);
        }
        float self = g1[(size_t)i * DD + c];
        acc = fmaf(di, fmaf(di, self, t), acc);
    }
    float inv = 1.0f / fmaxf((float)n, 1.0f);
    part[((size_t)sl * NG + g) * DD + c] = acc * inv;
}

// ---------------- small dense tail: dst[128x512] = (sum_sl src[sl]) @ W + bias ----------------
__global__ __launch_bounds__(256) void final_kernel(const float* __restrict__ src, int nslice,
                                                    const float* __restrict__ W,
                                                    const float* __restrict__ bias,
                                                    float* __restrict__ dst) {
    __shared__ float p[DD];
    int g = blockIdx.x;
    int t = threadIdx.x;
    float s0 = 0.f, s1 = 0.f;
    for (int sl = 0; sl < nslice; ++sl) {
        s0 += src[((size_t)sl * NG + g) * DD + t];
        s1 += src[((size_t)sl * NG + g) * DD + t + 256];
    }
    p[t] = s0;
    p[t + 256] = s1;
    __syncthreads();
    float a0 = bias[t], a1 = bias[t + 256];
    for (int k = 0; k < DD; ++k) {
        float pk = p[k];
        a0 = fmaf(pk, W[(size_t)k * DD + t], a0);
        a1 = fmaf(pk, W[(size_t)k * DD + t + 256], a1);
    }
    dst[(size_t)g * DD + t] = a0;
    dst[(size_t)g * DD + t + 256] = a1;
}

// ---------------- launch ----------------
extern "C" void kernel_launch(void* const* d_in, const int* in_sizes, int n_in,
                              void* d_out, int out_size, void* d_ws, size_t ws_size,
                              hipStream_t stream) {
    const float* x    = (const float*)d_in[0];
    const int*   ei   = (const int*)d_in[1];       // [2][160000], int32 or int64(lo,hi)
    const int*   batch= (const int*)d_in[2];
    const float* W1   = (const float*)d_in[3];
    const float* b1   = (const float*)d_in[4];
    const float* W2   = (const float*)d_in[5];
    const float* b2   = (const float*)d_in[6];
    const float* Wlin = (const float*)d_in[7];
    const float* blin = (const float*)d_in[8];
    float* out = (float*)d_out;

    // int64-vs-int32 layout detection (little-endian low word at stride 2)
    const int es = (in_sizes[1] == 2 * 2 * NE) ? 2 : 1;
    const int bs = (in_sizes[2] == 2 * NN) ? 2 : 1;
    const int* esrc = ei;
    const int* edst = ei + (size_t)NE * es;

    char* w = (char*)d_ws;
    auto alloc = [&](size_t bytes) { void* p = (void*)w; w += (bytes + 255) & ~(size_t)255; return p; };
    float* h      = (float*)alloc((size_t)NN * DD * 4);   // GEMM1 out; dead after agg ->
    float* part   = h;                                    //   reused as poolagg partials
    float* g      = (float*)alloc((size_t)NN * DD * 4);   // conv1 out (post-relu); before agg,
    short* xh     = (short*)g;                            //   aliased as xs bf16 hi (20.5 MB)
    short* xl     = (short*)g + (size_t)NN * DD;          //   and lo (20.5 MB) - dead after gemm
    short* W1h    = (short*)alloc((size_t)DD * DD * 2);   // W1^T bf16 hi
    short* W1l    = (short*)alloc((size_t)DD * DD * 2);   // bf16 lo
    float* tbuf   = (float*)alloc((size_t)NG * DD * 4);   // pooled@W2+b2
    float* rstd   = (float*)alloc(DD * 4);
    float* murs   = (float*)alloc(DD * 4);
    float* stats  = (float*)alloc(2 * DD * 4);            // colsum | colsq
    float* dis    = (float*)alloc(NN * 4);
    int*   deg    = (int*)alloc(NN * 4);
    int*   rowptr = (int*)alloc((NN + 4) * 4);
    int*   cursor = (int*)alloc(NN * 4);
    int*   csrsrc = (int*)alloc(NE * 4);
    float* colsum = stats;
    float* colsq  = stats + DD;

    // scaler stats -> rstd, mu*rstd; then standardize+split x, split W1^T
    hipMemsetAsync(stats, 0, 2 * DD * 4, stream);
    colstats_kernel<<<dim3(2, 200), 256, 0, stream>>>(x, colsum, colsq);
    finalize_kernel<<<1, 512, 0, stream>>>(colsum, colsq, rstd, murs);
    xsplit_kernel<<<10000, 256, 0, stream>>>(x, rstd, murs, xh, xl);
    wsplit_kernel<<<dim3(16, 16), 256, 0, stream>>>(W1, W1h, W1l);

    // graph structure
    deginit_kernel<<<(NN + 255) / 256, 256, 0, stream>>>(deg);
    degcount_kernel<<<NE / 256, 256, 0, stream>>>(edst, deg, es);
    dis_kernel<<<(NN + 255) / 256, 256, 0, stream>>>(deg, dis);
    scan_kernel<<<1, 1024, 0, stream>>>(deg, rowptr, cursor);
    scatter_kernel<<<NE / 256, 256, 0, stream>>>(esrc, edst, cursor, csrsrc, es);

    // conv1: h = xs @ W1 via split-bf16 MFMA (pipelined), then aggregate + b1 + relu -> g
    gemm_mfma_kernel<<<dim3((NN + 127) / 128, DD / 128), 256, 0, stream>>>(xh, xl, W1h, W1l, h, NN);
    agg_kernel<<<NN, 256, 0, stream>>>(h, g, dis, rowptr, csrsrc, b1, 1);
    // conv2 restructured: fused Agg+mean-pool from g, 16-way node-sliced
    poolagg_kernel<<<dim3(NG, 2, PSLICE), 256, 0, stream>>>(g, batch, bs, dis, rowptr, csrsrc, part);
    // tail: out = ((pooled @ W2 + b2) @ Wlin + blin)
    final_kernel<<<NG, 256, 0, stream>>>(part, PSLICE, W2, b2, tbuf);
    final_kernel<<<NG, 256, 0, stream>>>(tbuf, 1, Wlin, blin, out);
}